// Round 1
// baseline (334.214 us; speedup 1.0000x reference)
//
#include <hip/hip_runtime.h>

// Problem constants (from reference): B=16, S=4096, H=768, NUM_WORDS=2048.
constexpr int B = 16;
constexpr int S = 4096;
constexpr int H = 768;
constexpr int NW = 2048;
constexpr int V4 = H / 4;           // 192 float4 per token row
constexpr int WPW = 8;              // words per wave (streaming group)
constexpr int WAVES_PER_BLK = 4;    // 256-thread blocks
constexpr int GPS = NW / WPW;       // 256 word-groups per sample

// Phase 1: word_ids[b, 1..S-2] is non-decreasing (increments 0/1), sentinels
// -1 at s=0, s=S-1. Position s starts word row[s] iff row[s] != row[s-1].
// Entries for non-existent words (w > maxw) are never written and never read.
__global__ __launch_bounds__(256)
void find_starts_kernel(const int* __restrict__ wid, int* __restrict__ starts) {
    const int idx = blockIdx.x * 256 + threadIdx.x; // over B*S
    const int s = idx & (S - 1);
    const int b = idx >> 12;
    if (s < 1 || s >= S - 1) return;
    const int* __restrict__ row = wid + (size_t)b * S;
    const int cur = row[s];
    if (cur != row[s - 1] && cur >= 0) starts[b * NW + cur] = s;
}

__device__ __forceinline__ void acc4(float4& a, const float4 v) {
    a.x += v.x; a.y += v.y; a.z += v.z; a.w += v.w;
}

// Phase 2: one WAVE per 8 consecutive words of one sample (avg ~16 tokens ->
// ~48 KB contiguous reads + 24 KB contiguous writes per wave). Lane i of the
// first 10 lanes gathers all wave-uniform control data in ONE memory hop:
// lanes 0..8 -> starts[base+lane], lane 9 -> maxw. readlane puts boundaries
// into SGPRs so the whole control flow is wave-uniform scalar.
__global__ __launch_bounds__(64 * WAVES_PER_BLK)
void seg_mean_kernel(const float* __restrict__ hs,
                     const int* __restrict__ wid,
                     const int* __restrict__ starts,
                     float* __restrict__ out) {
    const int wave = threadIdx.x >> 6;
    const int lane = threadIdx.x & 63;
    const int gw = blockIdx.x * WAVES_PER_BLK + wave;  // global wave id
    const int b = gw >> 8;                             // / GPS
    const int w0 = (gw & (GPS - 1)) * WPW;
    const int base_blk = b * NW + w0;

    int ctrl;
    if (lane <= WPW) {
        const int i = base_blk + lane;
        ctrl = (i < B * NW) ? starts[i] : (S - 1);  // guard last group's +8
    } else if (lane == WPW + 1) {
        ctrl = wid[(size_t)b * S + (S - 2)];        // maxw for this sample
    } else {
        ctrl = 0;
    }
    const int maxw = __builtin_amdgcn_readlane(ctrl, WPW + 1);

    const float4* __restrict__ base = (const float4*)(hs + (size_t)b * S * H);
    float4* __restrict__ obase = (float4*)(out + (size_t)base_blk * H);

#pragma unroll
    for (int i = 0; i < WPW; ++i) {
        const int w = w0 + i;
        const int start = __builtin_amdgcn_readlane(ctrl, i);
        int end = (w == maxw) ? (S - 1) : __builtin_amdgcn_readlane(ctrl, i + 1);
        if (w > maxw) end = start;  // non-existent word -> zero tokens

        float4 a0 = make_float4(0.f, 0.f, 0.f, 0.f), a1 = a0, a2 = a0;
        int s = start;
        // 2-token unroll: 6 independent float4 loads in flight per lane.
        for (; s + 1 < end; s += 2) {
            const float4* p0 = base + (size_t)s * V4;
            const float4* p1 = p0 + V4;
            float4 v0 = p0[lane], v1 = p0[lane + 64], v2 = p0[lane + 128];
            float4 u0 = p1[lane], u1 = p1[lane + 64], u2 = p1[lane + 128];
            acc4(a0, v0); acc4(a1, v1); acc4(a2, v2);
            acc4(a0, u0); acc4(a1, u1); acc4(a2, u2);
        }
        if (s < end) {
            const float4* p0 = base + (size_t)s * V4;
            float4 v0 = p0[lane], v1 = p0[lane + 64], v2 = p0[lane + 128];
            acc4(a0, v0); acc4(a1, v1); acc4(a2, v2);
        }

        const int cnt = end - start;           // >=1 for existing words
        const float inv = 1.0f / (float)(cnt > 0 ? cnt : 1);
        a0.x *= inv; a0.y *= inv; a0.z *= inv; a0.w *= inv;
        a1.x *= inv; a1.y *= inv; a1.z *= inv; a1.w *= inv;
        a2.x *= inv; a2.y *= inv; a2.z *= inv; a2.w *= inv;

        float4* __restrict__ o = obase + (size_t)i * V4;
        o[lane] = a0; o[lane + 64] = a1; o[lane + 128] = a2;
    }
}

extern "C" void kernel_launch(void* const* d_in, const int* in_sizes, int n_in,
                              void* d_out, int out_size, void* d_ws, size_t ws_size,
                              hipStream_t stream) {
    const float* hs = (const float*)d_in[0];
    const int* wid = (const int*)d_in[1];
    float* out = (float*)d_out;
    int* starts = (int*)d_ws;  // B*NW ints = 128 KB scratch

    find_starts_kernel<<<(B * S) / 256, 256, 0, stream>>>(wid, starts);
    seg_mean_kernel<<<(B * GPS) / WAVES_PER_BLK, 64 * WAVES_PER_BLK, 0, stream>>>(
        hs, wid, starts, out);
}